// Round 1
// baseline (1012.419 us; speedup 1.0000x reference)
//
#include <hip/hip_runtime.h>
#include <hip/hip_bf16.h>
#include <math.h>

// Problem constants (fixed by reference): B=2,T=2048 -> N=4096 tokens
#define N_TOK 4096
#define D_DIM 1024
#define H_DIM 4096
#define E_NUM 8
#define NSLOT (N_TOK * 2)  // total assignments = N*TOPK = 8192

typedef short bf16x8 __attribute__((ext_vector_type(8)));
typedef float f32x4 __attribute__((ext_vector_type(4)));

// ---------------- helpers ----------------

__device__ __forceinline__ unsigned short f2bf(float f) {
  unsigned int u = __float_as_uint(f);
  u += 0x7FFFu + ((u >> 16) & 1u);  // round-to-nearest-even
  return (unsigned short)(u >> 16);
}

// async global->LDS, 16B per lane. LDS dest is wave-uniform base + lane*16;
// our dest addressing (t*16 within a 256-thread block) satisfies that per wave.
__device__ __forceinline__ void gld_lds16(const void* g, void* l) {
  __builtin_amdgcn_global_load_lds(
      (__attribute__((address_space(1))) void*)(g),
      (__attribute__((address_space(3))) void*)(l), 16, 0, 0);
}

// ---------------- small kernels ----------------

// zero the 256-byte control block (counts/cursor/offsets/sumP)
__global__ void init_ctrl(int* p) { p[threadIdx.x] = 0; }

__global__ void cvt_f32_bf16(const float* __restrict__ src,
                             unsigned short* __restrict__ dst, int n4) {
  int i = blockIdx.x * blockDim.x + threadIdx.x;
  if (i >= n4) return;
  float4 v = ((const float4*)src)[i];
  ushort4 o;
  o.x = f2bf(v.x); o.y = f2bf(v.y); o.z = f2bf(v.z); o.w = f2bf(v.w);
  ((ushort4*)dst)[i] = o;
}

__global__ void zero_f32(float* __restrict__ p, int n4) {
  int i = blockIdx.x * blockDim.x + threadIdx.x;
  if (i < n4) ((float4*)p)[i] = make_float4(0.f, 0.f, 0.f, 0.f);
}

// ---------------- gating: one block per token ----------------

__global__ void gating_kernel(const float* __restrict__ x,
                              const float* __restrict__ wg,
                              int* __restrict__ counts,
                              float* __restrict__ sumP,
                              int* __restrict__ eidx,
                              float* __restrict__ rw) {
  const int n = blockIdx.x;
  const int t = threadIdx.x;  // 256 threads
  const float* xr = x + (size_t)n * D_DIM;

  float part[E_NUM];
#pragma unroll
  for (int e = 0; e < E_NUM; ++e) part[e] = 0.f;
  for (int d = t; d < D_DIM; d += 256) {
    float xv = xr[d];
#pragma unroll
    for (int e = 0; e < E_NUM; ++e) part[e] += xv * wg[e * D_DIM + d];
  }

  __shared__ float red[256 * E_NUM];
#pragma unroll
  for (int e = 0; e < E_NUM; ++e) red[t * E_NUM + e] = part[e];
  __syncthreads();
  for (int s = 128; s > 0; s >>= 1) {
    if (t < s) {
#pragma unroll
      for (int e = 0; e < E_NUM; ++e)
        red[t * E_NUM + e] += red[(t + s) * E_NUM + e];
    }
    __syncthreads();
  }

  if (t == 0) {
    float l[E_NUM], p[E_NUM];
    float mx = -1e30f;
#pragma unroll
    for (int e = 0; e < E_NUM; ++e) { l[e] = red[e]; mx = fmaxf(mx, l[e]); }
    float s = 0.f;
#pragma unroll
    for (int e = 0; e < E_NUM; ++e) { p[e] = expf(l[e] - mx); s += p[e]; }
    float inv = 1.f / s;
    int i1 = 0;
#pragma unroll
    for (int e = 1; e < E_NUM; ++e) if (p[e] > p[i1]) i1 = e;
    int i2 = (i1 == 0) ? 1 : 0;
#pragma unroll
    for (int e = 0; e < E_NUM; ++e)
      if (e != i1 && p[e] > p[i2]) i2 = e;
#pragma unroll
    for (int e = 0; e < E_NUM; ++e) atomicAdd(&sumP[e], p[e] * inv);
    atomicAdd(&counts[i1], 1);
    atomicAdd(&counts[i2], 1);
    float p1 = p[i1], p2 = p[i2];
    float wsum = 1.f / (p1 + p2);  // renormalized top-2 (softmax scale cancels)
    eidx[n] = i1 | (i2 << 8);
    rw[2 * n] = p1 * wsum;
    rw[2 * n + 1] = p2 * wsum;
  }
}

// offsets scan (E=8, trivial) + balance loss
__global__ void scan_loss(const int* __restrict__ counts, int* __restrict__ offsets,
                          const float* __restrict__ sumP, float* __restrict__ loss) {
  if (threadIdx.x == 0) {
    int o = 0;
    float L = 0.f;
    for (int e = 0; e < E_NUM; ++e) {
      offsets[e] = o;
      o += counts[e];
      L += sumP[e] * (float)counts[e];
    }
    // E * sum_e mean_p[e] * (cnt[e]/N)  with mean_p = sumP/N
    loss[0] = L * (float)E_NUM / ((float)N_TOK * (float)N_TOK);
  }
}

__global__ void scatter_kernel(const int* __restrict__ eidx, const float* __restrict__ rw,
                               const int* __restrict__ offsets, int* __restrict__ cursor,
                               int* __restrict__ tok_id, float* __restrict__ tok_w) {
  int n = blockIdx.x * blockDim.x + threadIdx.x;
  if (n >= N_TOK) return;
  int pk = eidx[n];
  float w0 = rw[2 * n], w1 = rw[2 * n + 1];
  int e1 = pk & 255, e2 = pk >> 8;
  int pos = atomicAdd(&cursor[e1], 1);
  tok_id[offsets[e1] + pos] = n;
  tok_w[offsets[e1] + pos] = w0;
  pos = atomicAdd(&cursor[e2], 1);
  tok_id[offsets[e2] + pos] = n;
  tok_w[offsets[e2] + pos] = w1;
}

// ---------------- grouped GEMMs (m97 recipe: 128x128x64 tile, 4 waves) ----------------
// C[m][n] = sum_k A[m][k]*B[n][k]  (B^T form; both operands row-major along k)
// MFMA 16x16x32 bf16: A-frag lane(m=lane&15, k=(lane>>4)*8+j);
// C/D: col=lane&15, row=(lane>>4)*4+reg.

__launch_bounds__(256, 2)
__global__ void gemm_fc(const unsigned short* __restrict__ xb,    // [N_TOK][D]
                        const unsigned short* __restrict__ wfc,   // [E][H][D]
                        const int* __restrict__ tok_id,
                        const int* __restrict__ counts,
                        const int* __restrict__ offsets,
                        unsigned short* __restrict__ hbuf) {      // [NSLOT][H]
  const int e = blockIdx.z;
  const int cnt = counts[e];
  const int mtile = blockIdx.y;
  if (mtile * 128 >= cnt) return;
  const int ntile = blockIdx.x;
  const int off = offsets[e];

  __shared__ __align__(16) unsigned short As[128 * 64];
  __shared__ __align__(16) unsigned short Bs[128 * 64];

  const int t = threadIdx.x;
  const int lane = t & 63;
  const int wave = t >> 6;
  const int wm = (wave >> 1) * 64;
  const int wn = (wave & 1) * 64;
  const int seg = t & 7;    // 8 x 16B segments per 64-elem row
  const int srow = t >> 3;  // 0..31

  const unsigned short* aptr[4];
  const unsigned short* bptr[4];
#pragma unroll
  for (int p = 0; p < 4; ++p) {
    int r = mtile * 128 + p * 32 + srow;
    r = (r < cnt) ? r : (cnt - 1);  // clamp: masked at store
    int tok = tok_id[off + r];
    aptr[p] = xb + (size_t)tok * D_DIM + seg * 8;
    int br = ntile * 128 + p * 32 + srow;
    bptr[p] = wfc + ((size_t)e * H_DIM + br) * D_DIM + seg * 8;
  }

  f32x4 acc[4][4];
#pragma unroll
  for (int i = 0; i < 4; ++i)
#pragma unroll
    for (int j = 0; j < 4; ++j) acc[i][j] = (f32x4){0.f, 0.f, 0.f, 0.f};

  const int frow_a = wm + (lane & 15);
  const int frow_b = wn + (lane & 15);
  const int fcol = (lane >> 4) * 8;

  for (int k0 = 0; k0 < D_DIM; k0 += 64) {
#pragma unroll
    for (int p = 0; p < 4; ++p) {
      gld_lds16(aptr[p] + k0, &As[p * 2048 + t * 8]);
      gld_lds16(bptr[p] + k0, &Bs[p * 2048 + t * 8]);
    }
    __syncthreads();
#pragma unroll
    for (int kk = 0; kk < 64; kk += 32) {
      bf16x8 af[4], bfr[4];
#pragma unroll
      for (int i = 0; i < 4; ++i)
        af[i] = *(const bf16x8*)&As[(frow_a + i * 16) * 64 + kk + fcol];
#pragma unroll
      for (int j = 0; j < 4; ++j)
        bfr[j] = *(const bf16x8*)&Bs[(frow_b + j * 16) * 64 + kk + fcol];
#pragma unroll
      for (int i = 0; i < 4; ++i)
#pragma unroll
        for (int j = 0; j < 4; ++j)
          acc[i][j] = __builtin_amdgcn_mfma_f32_16x16x32_bf16(af[i], bfr[j], acc[i][j], 0, 0, 0);
    }
    __syncthreads();
  }

  // epilogue: h = relu(t)^2, cast bf16, store
  const int lm = (lane >> 4) * 4;
  const int ln = lane & 15;
#pragma unroll
  for (int i = 0; i < 4; ++i) {
#pragma unroll
    for (int r = 0; r < 4; ++r) {
      int m = mtile * 128 + wm + i * 16 + lm + r;
      if (m < cnt) {
        size_t rowbase = (size_t)(off + m) * H_DIM + ntile * 128 + wn;
#pragma unroll
        for (int j = 0; j < 4; ++j) {
          float v = acc[i][j][r];
          v = v > 0.f ? v * v : 0.f;
          hbuf[rowbase + j * 16 + ln] = f2bf(v);
        }
      }
    }
  }
}

__launch_bounds__(256, 2)
__global__ void gemm_proj(const unsigned short* __restrict__ hbuf,   // [NSLOT][H]
                          const unsigned short* __restrict__ wproj,  // [E][D][H]
                          const int* __restrict__ tok_id,
                          const float* __restrict__ tok_w,
                          const int* __restrict__ counts,
                          const int* __restrict__ offsets,
                          float* __restrict__ out) {                 // [N_TOK][D]
  const int e = blockIdx.z;
  const int cnt = counts[e];
  const int mtile = blockIdx.y;
  if (mtile * 128 >= cnt) return;
  const int ntile = blockIdx.x;  // 0..7 (D=1024)
  const int off = offsets[e];

  __shared__ __align__(16) unsigned short As[128 * 64];
  __shared__ __align__(16) unsigned short Bs[128 * 64];

  const int t = threadIdx.x;
  const int lane = t & 63;
  const int wave = t >> 6;
  const int wm = (wave >> 1) * 64;
  const int wn = (wave & 1) * 64;
  const int seg = t & 7;
  const int srow = t >> 3;

  const unsigned short* aptr[4];
  const unsigned short* bptr[4];
#pragma unroll
  for (int p = 0; p < 4; ++p) {
    int r = mtile * 128 + p * 32 + srow;
    r = (r < cnt) ? r : (cnt - 1);
    aptr[p] = hbuf + (size_t)(off + r) * H_DIM + seg * 8;
    int br = ntile * 128 + p * 32 + srow;
    bptr[p] = wproj + ((size_t)e * D_DIM + br) * H_DIM + seg * 8;
  }

  f32x4 acc[4][4];
#pragma unroll
  for (int i = 0; i < 4; ++i)
#pragma unroll
    for (int j = 0; j < 4; ++j) acc[i][j] = (f32x4){0.f, 0.f, 0.f, 0.f};

  const int frow_a = wm + (lane & 15);
  const int frow_b = wn + (lane & 15);
  const int fcol = (lane >> 4) * 8;

  for (int k0 = 0; k0 < H_DIM; k0 += 64) {
#pragma unroll
    for (int p = 0; p < 4; ++p) {
      gld_lds16(aptr[p] + k0, &As[p * 2048 + t * 8]);
      gld_lds16(bptr[p] + k0, &Bs[p * 2048 + t * 8]);
    }
    __syncthreads();
#pragma unroll
    for (int kk = 0; kk < 64; kk += 32) {
      bf16x8 af[4], bfr[4];
#pragma unroll
      for (int i = 0; i < 4; ++i)
        af[i] = *(const bf16x8*)&As[(frow_a + i * 16) * 64 + kk + fcol];
#pragma unroll
      for (int j = 0; j < 4; ++j)
        bfr[j] = *(const bf16x8*)&Bs[(frow_b + j * 16) * 64 + kk + fcol];
#pragma unroll
      for (int i = 0; i < 4; ++i)
#pragma unroll
        for (int j = 0; j < 4; ++j)
          acc[i][j] = __builtin_amdgcn_mfma_f32_16x16x32_bf16(af[i], bfr[j], acc[i][j], 0, 0, 0);
    }
    __syncthreads();
  }

  // epilogue: scale by routing weight, scatter-add into out (each element hit exactly TOPK=2 times)
  const int lm = (lane >> 4) * 4;
  const int ln = lane & 15;
#pragma unroll
  for (int i = 0; i < 4; ++i) {
#pragma unroll
    for (int r = 0; r < 4; ++r) {
      int m = mtile * 128 + wm + i * 16 + lm + r;
      if (m < cnt) {
        int slot = off + m;
        float w = tok_w[slot];
        float* orow = out + (size_t)tok_id[slot] * D_DIM + ntile * 128 + wn;
#pragma unroll
        for (int j = 0; j < 4; ++j)
          atomicAdd(&orow[j * 16 + ln], acc[i][j][r] * w);
      }
    }
  }
}

// ---------------- launch ----------------
// ws layout (bytes, all 256-aligned):
//   0       counts[8] | 64 cursor[8] | 128 offsets[8] | 192 sumP[8]
//   256     eidx[4096]            (16384)
//   16640   rw[8192]              (32768)
//   49408   tok_id[8192]          (32768)
//   82176   tok_w[8192]           (32768)
//   114944  x_bf16   [4096*1024]  (8388608)
//   8503552 wfc_bf16 [8*4096*1024](67108864)
//   75612416 wproj_bf16           (67108864)
//   142721280 hbuf [8192*4096]    (67108864)
//   total: 209830144 (~200 MiB)

extern "C" void kernel_launch(void* const* d_in, const int* in_sizes, int n_in,
                              void* d_out, int out_size, void* d_ws, size_t ws_size,
                              hipStream_t stream) {
  (void)in_sizes; (void)n_in; (void)out_size; (void)ws_size;
  const float* x = (const float*)d_in[0];
  const float* wg = (const float*)d_in[1];
  const float* wfc = (const float*)d_in[2];
  const float* wproj = (const float*)d_in[3];
  float* out = (float*)d_out;
  char* ws = (char*)d_ws;

  int* counts = (int*)(ws + 0);
  int* cursor = (int*)(ws + 64);
  int* offsets = (int*)(ws + 128);
  float* sumP = (float*)(ws + 192);
  int* eidx = (int*)(ws + 256);
  float* rw = (float*)(ws + 16640);
  int* tok_id = (int*)(ws + 49408);
  float* tok_w = (float*)(ws + 82176);
  unsigned short* xb = (unsigned short*)(ws + 114944);
  unsigned short* wfcb = (unsigned short*)(ws + 8503552);
  unsigned short* wpjb = (unsigned short*)(ws + 75612416);
  unsigned short* hbuf = (unsigned short*)(ws + 142721280);

  hipLaunchKernelGGL(init_ctrl, dim3(1), dim3(64), 0, stream, (int*)ws);
  hipLaunchKernelGGL(cvt_f32_bf16, dim3(32768), dim3(256), 0, stream, wfc, wfcb, 8388608);
  hipLaunchKernelGGL(cvt_f32_bf16, dim3(32768), dim3(256), 0, stream, wproj, wpjb, 8388608);
  hipLaunchKernelGGL(cvt_f32_bf16, dim3(4096), dim3(256), 0, stream, x, xb, 1048576);
  hipLaunchKernelGGL(zero_f32, dim3(4096), dim3(256), 0, stream, out, 1048576);
  hipLaunchKernelGGL(gating_kernel, dim3(4096), dim3(256), 0, stream, x, wg, counts, sumP, eidx, rw);
  hipLaunchKernelGGL(scan_loss, dim3(1), dim3(64), 0, stream, counts, offsets, sumP, out + 4194304);
  hipLaunchKernelGGL(scatter_kernel, dim3(16), dim3(256), 0, stream, eidx, rw, offsets, cursor, tok_id, tok_w);
  // worst-case grids (cnt<=4096 -> 32 M-tiles); blocks beyond cnt exit immediately
  hipLaunchKernelGGL(gemm_fc, dim3(32, 32, 8), dim3(256), 0, stream, xb, wfcb, tok_id, counts, offsets, hbuf);
  hipLaunchKernelGGL(gemm_proj, dim3(8, 32, 8), dim3(256), 0, stream, hbuf, wpjb, tok_id, tok_w, counts, offsets, out);
}

// Round 2
// 583.771 us; speedup vs baseline: 1.7343x; 1.7343x over previous
//
#include <hip/hip_runtime.h>
#include <hip/hip_bf16.h>
#include <math.h>

// Problem constants (fixed by reference): B=2,T=2048 -> N=4096 tokens
#define N_TOK 4096
#define D_DIM 1024
#define H_DIM 4096
#define E_NUM 8
#define NSLOT (N_TOK * 2)  // total assignments = N*TOPK = 8192

typedef short bf16x8 __attribute__((ext_vector_type(8)));
typedef float f32x4 __attribute__((ext_vector_type(4)));

// ---------------- helpers ----------------

__device__ __forceinline__ unsigned short f2bf(float f) {
  unsigned int u = __float_as_uint(f);
  u += 0x7FFFu + ((u >> 16) & 1u);  // round-to-nearest-even
  return (unsigned short)(u >> 16);
}

// async global->LDS, 16B per lane. LDS dest is wave-uniform base + lane*16;
// our dest addressing (t*16 within a 256-thread block) satisfies that per wave.
__device__ __forceinline__ void gld_lds16(const void* g, void* l) {
  __builtin_amdgcn_global_load_lds(
      (__attribute__((address_space(1))) void*)(g),
      (__attribute__((address_space(3))) void*)(l), 16, 0, 0);
}

// ---------------- small kernels ----------------

// zero the 256-byte control block (counts/cursor/offsets/sumP)
__global__ void init_ctrl(int* p) { p[threadIdx.x] = 0; }

__global__ void cvt_f32_bf16(const float* __restrict__ src,
                             unsigned short* __restrict__ dst, int n4) {
  int i = blockIdx.x * blockDim.x + threadIdx.x;
  if (i >= n4) return;
  float4 v = ((const float4*)src)[i];
  ushort4 o;
  o.x = f2bf(v.x); o.y = f2bf(v.y); o.z = f2bf(v.z); o.w = f2bf(v.w);
  ((ushort4*)dst)[i] = o;
}

__global__ void zero_f32(float* __restrict__ p, int n4) {
  int i = blockIdx.x * blockDim.x + threadIdx.x;
  if (i < n4) ((float4*)p)[i] = make_float4(0.f, 0.f, 0.f, 0.f);
}

// ---------------- gating: atomic-free ----------------
// 256 blocks x 16 tokens. W_gate staged in LDS once per block. One wave per
// token (waves iterate over 4 tokens each); 64-lane butterfly reduction; no
// global atomics -- normalized probs written to ws for a later reduction.

__global__ void gating_kernel(const float* __restrict__ x,
                              const float* __restrict__ wg,
                              float* __restrict__ probs,   // [N_TOK][E]
                              int* __restrict__ eidx,
                              float* __restrict__ rw) {
  __shared__ float4 wg_lds[2048];  // 8*1024 floats = 32 KB
  const int t = threadIdx.x;
  const int lane = t & 63;
  const int wave = t >> 6;

#pragma unroll
  for (int j = 0; j < 8; ++j)
    wg_lds[t + 256 * j] = ((const float4*)wg)[t + 256 * j];
  __syncthreads();

#pragma unroll
  for (int j = 0; j < 4; ++j) {
    const int n = blockIdx.x * 16 + wave * 4 + j;
    const float4* xr = (const float4*)(x + (size_t)n * D_DIM);

    float acc[E_NUM];
#pragma unroll
    for (int e = 0; e < E_NUM; ++e) acc[e] = 0.f;

#pragma unroll
    for (int i = 0; i < 4; ++i) {
      float4 xv = xr[lane + 64 * i];
#pragma unroll
      for (int e = 0; e < E_NUM; ++e) {
        float4 wv = wg_lds[e * 256 + lane + 64 * i];
        acc[e] += xv.x * wv.x + xv.y * wv.y + xv.z * wv.z + xv.w * wv.w;
      }
    }
    // 64-lane butterfly: every lane ends with the full dot products
#pragma unroll
    for (int m = 1; m < 64; m <<= 1) {
#pragma unroll
      for (int e = 0; e < E_NUM; ++e) acc[e] += __shfl_xor(acc[e], m, 64);
    }

    // softmax + top2 (all lanes redundantly; cheap, no divergence)
    float mx = acc[0];
#pragma unroll
    for (int e = 1; e < E_NUM; ++e) mx = fmaxf(mx, acc[e]);
    float p[E_NUM], s = 0.f;
#pragma unroll
    for (int e = 0; e < E_NUM; ++e) { p[e] = __expf(acc[e] - mx); s += p[e]; }
    float inv = 1.f / s;

    if (lane < E_NUM) probs[(size_t)n * E_NUM + lane] = p[lane] * inv;

    if (lane == 0) {
      int i1 = 0;
#pragma unroll
      for (int e = 1; e < E_NUM; ++e) if (p[e] > p[i1]) i1 = e;
      int i2 = (i1 == 0) ? 1 : 0;
#pragma unroll
      for (int e = 0; e < E_NUM; ++e)
        if (e != i1 && p[e] > p[i2]) i2 = e;
      float p1 = p[i1], p2 = p[i2];
      float wsum = 1.f / (p1 + p2);  // top-2 renormalize (softmax scale cancels)
      eidx[n] = i1 | (i2 << 8);
      rw[2 * n] = p1 * wsum;
      rw[2 * n + 1] = p2 * wsum;
    }
  }
}

// single block: sumP column-sums, expert histogram, offsets, balance loss
__global__ void reduce_route(const float* __restrict__ probs,
                             const int* __restrict__ eidx,
                             int* __restrict__ counts,
                             int* __restrict__ offsets,
                             float* __restrict__ loss) {
  const int t = threadIdx.x;
  // --- prob partial sums (coalesced float4; parity(t) fixes expert group) ---
  float4 part = make_float4(0.f, 0.f, 0.f, 0.f);
  for (int j = 0; j < 32; ++j) {
    float4 v = ((const float4*)probs)[t + 256 * j];
    part.x += v.x; part.y += v.y; part.z += v.z; part.w += v.w;
  }
  // --- register histogram of expert assignments ---
  int cnt[E_NUM];
#pragma unroll
  for (int e = 0; e < E_NUM; ++e) cnt[e] = 0;
  for (int j = 0; j < 16; ++j) {
    int pk = eidx[t + 256 * j];
    int e1 = pk & 255, e2 = pk >> 8;
#pragma unroll
    for (int e = 0; e < E_NUM; ++e) cnt[e] += (e1 == e) + (e2 == e);
  }

  __shared__ float redf[256 * E_NUM];
  __shared__ int redi[256 * E_NUM];
  const int eb = (t & 1) * 4;  // this thread's expert group base
#pragma unroll
  for (int e = 0; e < E_NUM; ++e) { redf[t * E_NUM + e] = 0.f; redi[t * E_NUM + e] = cnt[e]; }
  redf[t * E_NUM + eb + 0] = part.x;
  redf[t * E_NUM + eb + 1] = part.y;
  redf[t * E_NUM + eb + 2] = part.z;
  redf[t * E_NUM + eb + 3] = part.w;
  __syncthreads();
  for (int s = 128; s > 0; s >>= 1) {
    if (t < s) {
#pragma unroll
      for (int e = 0; e < E_NUM; ++e) {
        redf[t * E_NUM + e] += redf[(t + s) * E_NUM + e];
        redi[t * E_NUM + e] += redi[(t + s) * E_NUM + e];
      }
    }
    __syncthreads();
  }
  if (t == 0) {
    int o = 0;
    float L = 0.f;
    for (int e = 0; e < E_NUM; ++e) {
      int c = redi[e];
      counts[e] = c;
      offsets[e] = o;
      o += c;
      L += redf[e] * (float)c;
    }
    loss[0] = L * (float)E_NUM / ((float)N_TOK * (float)N_TOK);
  }
}

// two-phase scatter: LDS-local bucket positions, one global atomic per
// expert per block (16 blocks x 8 = 128 contended atomics total)
__global__ void scatter_kernel(const int* __restrict__ eidx, const float* __restrict__ rw,
                               const int* __restrict__ offsets, int* __restrict__ cursor,
                               int* __restrict__ tok_id, float* __restrict__ tok_w) {
  __shared__ int lcnt[E_NUM];
  __shared__ int lbase[E_NUM];
  const int t = threadIdx.x;
  const int n = blockIdx.x * 256 + t;
  if (t < E_NUM) lcnt[t] = 0;
  __syncthreads();
  int pk = eidx[n];
  int e1 = pk & 255, e2 = pk >> 8;
  int p1 = atomicAdd(&lcnt[e1], 1);
  int p2 = atomicAdd(&lcnt[e2], 1);
  __syncthreads();
  if (t < E_NUM) lbase[t] = atomicAdd(&cursor[t], lcnt[t]);
  __syncthreads();
  int d1 = offsets[e1] + lbase[e1] + p1;
  tok_id[d1] = n; tok_w[d1] = rw[2 * n];
  int d2 = offsets[e2] + lbase[e2] + p2;
  tok_id[d2] = n; tok_w[d2] = rw[2 * n + 1];
}

// ---------------- grouped GEMMs (m97 recipe: 128x128x64 tile, 4 waves) ----------------
// C[m][n] = sum_k A[m][k]*B[n][k]  (B^T form; both operands row-major along k)
// MFMA 16x16x32 bf16: A-frag lane(m=lane&15, k=(lane>>4)*8+j);
// C/D: col=lane&15, row=(lane>>4)*4+reg.

__launch_bounds__(256, 2)
__global__ void gemm_fc(const unsigned short* __restrict__ xb,    // [N_TOK][D]
                        const unsigned short* __restrict__ wfc,   // [E][H][D]
                        const int* __restrict__ tok_id,
                        const int* __restrict__ counts,
                        const int* __restrict__ offsets,
                        unsigned short* __restrict__ hbuf) {      // [NSLOT][H]
  const int e = blockIdx.z;
  const int cnt = counts[e];
  const int mtile = blockIdx.y;
  if (mtile * 128 >= cnt) return;
  const int ntile = blockIdx.x;
  const int off = offsets[e];

  __shared__ __align__(16) unsigned short As[128 * 64];
  __shared__ __align__(16) unsigned short Bs[128 * 64];

  const int t = threadIdx.x;
  const int lane = t & 63;
  const int wave = t >> 6;
  const int wm = (wave >> 1) * 64;
  const int wn = (wave & 1) * 64;
  const int seg = t & 7;    // 8 x 16B segments per 64-elem row
  const int srow = t >> 3;  // 0..31

  const unsigned short* aptr[4];
  const unsigned short* bptr[4];
#pragma unroll
  for (int p = 0; p < 4; ++p) {
    int r = mtile * 128 + p * 32 + srow;
    r = (r < cnt) ? r : (cnt - 1);  // clamp: masked at store
    int tok = tok_id[off + r];
    aptr[p] = xb + (size_t)tok * D_DIM + seg * 8;
    int br = ntile * 128 + p * 32 + srow;
    bptr[p] = wfc + ((size_t)e * H_DIM + br) * D_DIM + seg * 8;
  }

  f32x4 acc[4][4];
#pragma unroll
  for (int i = 0; i < 4; ++i)
#pragma unroll
    for (int j = 0; j < 4; ++j) acc[i][j] = (f32x4){0.f, 0.f, 0.f, 0.f};

  const int frow_a = wm + (lane & 15);
  const int frow_b = wn + (lane & 15);
  const int fcol = (lane >> 4) * 8;

  for (int k0 = 0; k0 < D_DIM; k0 += 64) {
#pragma unroll
    for (int p = 0; p < 4; ++p) {
      gld_lds16(aptr[p] + k0, &As[p * 2048 + t * 8]);
      gld_lds16(bptr[p] + k0, &Bs[p * 2048 + t * 8]);
    }
    __syncthreads();
#pragma unroll
    for (int kk = 0; kk < 64; kk += 32) {
      bf16x8 af[4], bfr[4];
#pragma unroll
      for (int i = 0; i < 4; ++i)
        af[i] = *(const bf16x8*)&As[(frow_a + i * 16) * 64 + kk + fcol];
#pragma unroll
      for (int j = 0; j < 4; ++j)
        bfr[j] = *(const bf16x8*)&Bs[(frow_b + j * 16) * 64 + kk + fcol];
#pragma unroll
      for (int i = 0; i < 4; ++i)
#pragma unroll
        for (int j = 0; j < 4; ++j)
          acc[i][j] = __builtin_amdgcn_mfma_f32_16x16x32_bf16(af[i], bfr[j], acc[i][j], 0, 0, 0);
    }
    __syncthreads();
  }

  // epilogue: h = relu(t)^2, cast bf16, store
  const int lm = (lane >> 4) * 4;
  const int ln = lane & 15;
#pragma unroll
  for (int i = 0; i < 4; ++i) {
#pragma unroll
    for (int r = 0; r < 4; ++r) {
      int m = mtile * 128 + wm + i * 16 + lm + r;
      if (m < cnt) {
        size_t rowbase = (size_t)(off + m) * H_DIM + ntile * 128 + wn;
#pragma unroll
        for (int j = 0; j < 4; ++j) {
          float v = acc[i][j][r];
          v = v > 0.f ? v * v : 0.f;
          hbuf[rowbase + j * 16 + ln] = f2bf(v);
        }
      }
    }
  }
}

__launch_bounds__(256, 2)
__global__ void gemm_proj(const unsigned short* __restrict__ hbuf,   // [NSLOT][H]
                          const unsigned short* __restrict__ wproj,  // [E][D][H]
                          const int* __restrict__ tok_id,
                          const float* __restrict__ tok_w,
                          const int* __restrict__ counts,
                          const int* __restrict__ offsets,
                          float* __restrict__ out) {                 // [N_TOK][D]
  const int e = blockIdx.z;
  const int cnt = counts[e];
  const int mtile = blockIdx.y;
  if (mtile * 128 >= cnt) return;
  const int ntile = blockIdx.x;  // 0..7 (D=1024)
  const int off = offsets[e];

  __shared__ __align__(16) unsigned short As[128 * 64];
  __shared__ __align__(16) unsigned short Bs[128 * 64];

  const int t = threadIdx.x;
  const int lane = t & 63;
  const int wave = t >> 6;
  const int wm = (wave >> 1) * 64;
  const int wn = (wave & 1) * 64;
  const int seg = t & 7;
  const int srow = t >> 3;

  const unsigned short* aptr[4];
  const unsigned short* bptr[4];
#pragma unroll
  for (int p = 0; p < 4; ++p) {
    int r = mtile * 128 + p * 32 + srow;
    r = (r < cnt) ? r : (cnt - 1);
    aptr[p] = hbuf + (size_t)(off + r) * H_DIM + seg * 8;
    int br = ntile * 128 + p * 32 + srow;
    bptr[p] = wproj + ((size_t)e * D_DIM + br) * H_DIM + seg * 8;
  }

  f32x4 acc[4][4];
#pragma unroll
  for (int i = 0; i < 4; ++i)
#pragma unroll
    for (int j = 0; j < 4; ++j) acc[i][j] = (f32x4){0.f, 0.f, 0.f, 0.f};

  const int frow_a = wm + (lane & 15);
  const int frow_b = wn + (lane & 15);
  const int fcol = (lane >> 4) * 8;

  for (int k0 = 0; k0 < H_DIM; k0 += 64) {
#pragma unroll
    for (int p = 0; p < 4; ++p) {
      gld_lds16(aptr[p] + k0, &As[p * 2048 + t * 8]);
      gld_lds16(bptr[p] + k0, &Bs[p * 2048 + t * 8]);
    }
    __syncthreads();
#pragma unroll
    for (int kk = 0; kk < 64; kk += 32) {
      bf16x8 af[4], bfr[4];
#pragma unroll
      for (int i = 0; i < 4; ++i)
        af[i] = *(const bf16x8*)&As[(frow_a + i * 16) * 64 + kk + fcol];
#pragma unroll
      for (int j = 0; j < 4; ++j)
        bfr[j] = *(const bf16x8*)&Bs[(frow_b + j * 16) * 64 + kk + fcol];
#pragma unroll
      for (int i = 0; i < 4; ++i)
#pragma unroll
        for (int j = 0; j < 4; ++j)
          acc[i][j] = __builtin_amdgcn_mfma_f32_16x16x32_bf16(af[i], bfr[j], acc[i][j], 0, 0, 0);
    }
    __syncthreads();
  }

  // epilogue: scale by routing weight, scatter-add into out (each element hit exactly TOPK=2 times)
  const int lm = (lane >> 4) * 4;
  const int ln = lane & 15;
#pragma unroll
  for (int i = 0; i < 4; ++i) {
#pragma unroll
    for (int r = 0; r < 4; ++r) {
      int m = mtile * 128 + wm + i * 16 + lm + r;
      if (m < cnt) {
        int slot = off + m;
        float w = tok_w[slot];
        float* orow = out + (size_t)tok_id[slot] * D_DIM + ntile * 128 + wn;
#pragma unroll
        for (int j = 0; j < 4; ++j)
          atomicAdd(&orow[j * 16 + ln], acc[i][j][r] * w);
      }
    }
  }
}

// ---------------- launch ----------------
// ws layout (bytes, all 256-aligned):
//   0        counts[8] | 64 cursor[8] | 128 offsets[8] | 192 spare
//   256      eidx[4096]            (16384)
//   16640    rw[8192]              (32768)
//   49408    tok_id[8192]          (32768)
//   82176    tok_w[8192]           (32768)
//   114944   probs[4096*8]         (131072)
//   246016   x_bf16   [4096*1024]  (8388608)
//   8634624  wfc_bf16 [8*4096*1024](67108864)
//   75743488 wproj_bf16            (67108864)
//   142852352 hbuf [8192*4096]     (67108864)
//   total: 209961216 (~200 MiB)

extern "C" void kernel_launch(void* const* d_in, const int* in_sizes, int n_in,
                              void* d_out, int out_size, void* d_ws, size_t ws_size,
                              hipStream_t stream) {
  (void)in_sizes; (void)n_in; (void)out_size; (void)ws_size;
  const float* x = (const float*)d_in[0];
  const float* wg = (const float*)d_in[1];
  const float* wfc = (const float*)d_in[2];
  const float* wproj = (const float*)d_in[3];
  float* out = (float*)d_out;
  char* ws = (char*)d_ws;

  int* counts = (int*)(ws + 0);
  int* cursor = (int*)(ws + 64);
  int* offsets = (int*)(ws + 128);
  int* eidx = (int*)(ws + 256);
  float* rw = (float*)(ws + 16640);
  int* tok_id = (int*)(ws + 49408);
  float* tok_w = (float*)(ws + 82176);
  float* probs = (float*)(ws + 114944);
  unsigned short* xb = (unsigned short*)(ws + 246016);
  unsigned short* wfcb = (unsigned short*)(ws + 8634624);
  unsigned short* wpjb = (unsigned short*)(ws + 75743488);
  unsigned short* hbuf = (unsigned short*)(ws + 142852352);

  hipLaunchKernelGGL(init_ctrl, dim3(1), dim3(64), 0, stream, (int*)ws);
  hipLaunchKernelGGL(cvt_f32_bf16, dim3(32768), dim3(256), 0, stream, wfc, wfcb, 8388608);
  hipLaunchKernelGGL(cvt_f32_bf16, dim3(32768), dim3(256), 0, stream, wproj, wpjb, 8388608);
  hipLaunchKernelGGL(cvt_f32_bf16, dim3(4096), dim3(256), 0, stream, x, xb, 1048576);
  hipLaunchKernelGGL(zero_f32, dim3(4096), dim3(256), 0, stream, out, 1048576);
  hipLaunchKernelGGL(gating_kernel, dim3(256), dim3(256), 0, stream, x, wg, probs, eidx, rw);
  hipLaunchKernelGGL(reduce_route, dim3(1), dim3(256), 0, stream, probs, eidx, counts, offsets, out + 4194304);
  hipLaunchKernelGGL(scatter_kernel, dim3(16), dim3(256), 0, stream, eidx, rw, offsets, cursor, tok_id, tok_w);
  // worst-case grids (cnt<=4096 -> 32 M-tiles); blocks beyond cnt exit immediately
  hipLaunchKernelGGL(gemm_fc, dim3(32, 32, 8), dim3(256), 0, stream, xb, wfcb, tok_id, counts, offsets, hbuf);
  hipLaunchKernelGGL(gemm_proj, dim3(8, 32, 8), dim3(256), 0, stream, hbuf, wpjb, tok_id, tok_w, counts, offsets, out);
}

// Round 3
// 561.966 us; speedup vs baseline: 1.8016x; 1.0388x over previous
//
#include <hip/hip_runtime.h>
#include <hip/hip_bf16.h>
#include <math.h>

// Problem constants (fixed by reference): B=2,T=2048 -> N=4096 tokens
#define N_TOK 4096
#define D_DIM 1024
#define H_DIM 4096
#define E_NUM 8
#define NSLOT (N_TOK * 2)  // total assignments = N*TOPK = 8192

typedef short bf16x8 __attribute__((ext_vector_type(8)));
typedef float f32x4 __attribute__((ext_vector_type(4)));

// ---------------- helpers ----------------

__device__ __forceinline__ unsigned short f2bf(float f) {
  unsigned int u = __float_as_uint(f);
  u += 0x7FFFu + ((u >> 16) & 1u);  // round-to-nearest-even
  return (unsigned short)(u >> 16);
}

// async global->LDS, 16B per lane. LDS dest is wave-uniform base + lane*16
// (m104: per-lane scatter impossible; hence the XOR *source* swizzle below).
__device__ __forceinline__ void gld_lds16(const void* g, void* l) {
  __builtin_amdgcn_global_load_lds(
      (__attribute__((address_space(1))) void*)(g),
      (__attribute__((address_space(3))) void*)(l), 16, 0, 0);
}

// ---------------- small kernels ----------------

__global__ void init_ctrl(int* p) { p[threadIdx.x] = 0; }

__global__ void cvt_f32_bf16(const float* __restrict__ src,
                             unsigned short* __restrict__ dst, int n4) {
  int i = blockIdx.x * blockDim.x + threadIdx.x;
  if (i >= n4) return;
  float4 v = ((const float4*)src)[i];
  ushort4 o;
  o.x = f2bf(v.x); o.y = f2bf(v.y); o.z = f2bf(v.z); o.w = f2bf(v.w);
  ((ushort4*)dst)[i] = o;
}

__global__ void zero_f32(float* __restrict__ p, int n4) {
  int i = blockIdx.x * blockDim.x + threadIdx.x;
  if (i < n4) ((float4*)p)[i] = make_float4(0.f, 0.f, 0.f, 0.f);
}

// ---------------- gating: atomic-free ----------------

__global__ void gating_kernel(const float* __restrict__ x,
                              const float* __restrict__ wg,
                              float* __restrict__ probs,   // [N_TOK][E]
                              int* __restrict__ eidx,
                              float* __restrict__ rw) {
  __shared__ float4 wg_lds[2048];  // 8*1024 floats = 32 KB
  const int t = threadIdx.x;
  const int lane = t & 63;
  const int wave = t >> 6;

#pragma unroll
  for (int j = 0; j < 8; ++j)
    wg_lds[t + 256 * j] = ((const float4*)wg)[t + 256 * j];
  __syncthreads();

#pragma unroll
  for (int j = 0; j < 4; ++j) {
    const int n = blockIdx.x * 16 + wave * 4 + j;
    const float4* xr = (const float4*)(x + (size_t)n * D_DIM);

    float acc[E_NUM];
#pragma unroll
    for (int e = 0; e < E_NUM; ++e) acc[e] = 0.f;

#pragma unroll
    for (int i = 0; i < 4; ++i) {
      float4 xv = xr[lane + 64 * i];
#pragma unroll
      for (int e = 0; e < E_NUM; ++e) {
        float4 wv = wg_lds[e * 256 + lane + 64 * i];
        acc[e] += xv.x * wv.x + xv.y * wv.y + xv.z * wv.z + xv.w * wv.w;
      }
    }
#pragma unroll
    for (int m = 1; m < 64; m <<= 1) {
#pragma unroll
      for (int e = 0; e < E_NUM; ++e) acc[e] += __shfl_xor(acc[e], m, 64);
    }

    float mx = acc[0];
#pragma unroll
    for (int e = 1; e < E_NUM; ++e) mx = fmaxf(mx, acc[e]);
    float p[E_NUM], s = 0.f;
#pragma unroll
    for (int e = 0; e < E_NUM; ++e) { p[e] = __expf(acc[e] - mx); s += p[e]; }
    float inv = 1.f / s;

    if (lane < E_NUM) probs[(size_t)n * E_NUM + lane] = p[lane] * inv;

    if (lane == 0) {
      int i1 = 0;
#pragma unroll
      for (int e = 1; e < E_NUM; ++e) if (p[e] > p[i1]) i1 = e;
      int i2 = (i1 == 0) ? 1 : 0;
#pragma unroll
      for (int e = 0; e < E_NUM; ++e)
        if (e != i1 && p[e] > p[i2]) i2 = e;
      float p1 = p[i1], p2 = p[i2];
      float wsum = 1.f / (p1 + p2);  // top-2 renormalize (softmax scale cancels)
      eidx[n] = i1 | (i2 << 8);
      rw[2 * n] = p1 * wsum;
      rw[2 * n + 1] = p2 * wsum;
    }
  }
}

// single block: sumP column-sums, expert histogram, offsets, balance loss
__global__ void reduce_route(const float* __restrict__ probs,
                             const int* __restrict__ eidx,
                             int* __restrict__ counts,
                             int* __restrict__ offsets,
                             float* __restrict__ loss) {
  const int t = threadIdx.x;
  float4 part = make_float4(0.f, 0.f, 0.f, 0.f);
  for (int j = 0; j < 32; ++j) {
    float4 v = ((const float4*)probs)[t + 256 * j];
    part.x += v.x; part.y += v.y; part.z += v.z; part.w += v.w;
  }
  int cnt[E_NUM];
#pragma unroll
  for (int e = 0; e < E_NUM; ++e) cnt[e] = 0;
  for (int j = 0; j < 16; ++j) {
    int pk = eidx[t + 256 * j];
    int e1 = pk & 255, e2 = pk >> 8;
#pragma unroll
    for (int e = 0; e < E_NUM; ++e) cnt[e] += (e1 == e) + (e2 == e);
  }

  __shared__ float redf[256 * E_NUM];
  __shared__ int redi[256 * E_NUM];
  const int eb = (t & 1) * 4;
#pragma unroll
  for (int e = 0; e < E_NUM; ++e) { redf[t * E_NUM + e] = 0.f; redi[t * E_NUM + e] = cnt[e]; }
  redf[t * E_NUM + eb + 0] = part.x;
  redf[t * E_NUM + eb + 1] = part.y;
  redf[t * E_NUM + eb + 2] = part.z;
  redf[t * E_NUM + eb + 3] = part.w;
  __syncthreads();
  for (int s = 128; s > 0; s >>= 1) {
    if (t < s) {
#pragma unroll
      for (int e = 0; e < E_NUM; ++e) {
        redf[t * E_NUM + e] += redf[(t + s) * E_NUM + e];
        redi[t * E_NUM + e] += redi[(t + s) * E_NUM + e];
      }
    }
    __syncthreads();
  }
  if (t == 0) {
    int o = 0;
    float L = 0.f;
    for (int e = 0; e < E_NUM; ++e) {
      int c = redi[e];
      counts[e] = c;
      offsets[e] = o;
      o += c;
      L += redf[e] * (float)c;
    }
    loss[0] = L * (float)E_NUM / ((float)N_TOK * (float)N_TOK);
  }
}

// two-phase scatter: LDS-local positions, one global atomic per expert/block
__global__ void scatter_kernel(const int* __restrict__ eidx, const float* __restrict__ rw,
                               const int* __restrict__ offsets, int* __restrict__ cursor,
                               int* __restrict__ tok_id, float* __restrict__ tok_w) {
  __shared__ int lcnt[E_NUM];
  __shared__ int lbase[E_NUM];
  const int t = threadIdx.x;
  const int n = blockIdx.x * 256 + t;
  if (t < E_NUM) lcnt[t] = 0;
  __syncthreads();
  int pk = eidx[n];
  int e1 = pk & 255, e2 = pk >> 8;
  int p1 = atomicAdd(&lcnt[e1], 1);
  int p2 = atomicAdd(&lcnt[e2], 1);
  __syncthreads();
  if (t < E_NUM) lbase[t] = atomicAdd(&cursor[t], lcnt[t]);
  __syncthreads();
  int d1 = offsets[e1] + lbase[e1] + p1;
  tok_id[d1] = n; tok_w[d1] = rw[2 * n];
  int d2 = offsets[e2] + lbase[e2] + p2;
  tok_id[d2] = n; tok_w[d2] = rw[2 * n + 1];
}

// ---------------- grouped GEMMs ----------------
// 128x128x64 tile, 4 waves. C[m][n] = sum_k A[m][k]*B[n][k] (both row-major in k).
// LDS bank fix: row stride is 64 bf16 = 32 banks, so bank = f(col) only ->
// naive frag reads are 16-way conflicted (R2: 2.6e7 SQ_LDS_BANK_CONFLICT).
// XOR swizzle: LDS[row][chunk c] holds global chunk c ^ (row&7); readers use
// chunk ((kk>>3)+q) ^ (lane&7) -> 8 distinct bank groups per quarter-wave,
// 2-way aliasing only (free, m136). global_load_lds dest stays contiguous.

__launch_bounds__(256, 2)
__global__ void gemm_fc(const unsigned short* __restrict__ xb,    // [N_TOK][D]
                        const unsigned short* __restrict__ wfc,   // [E][H][D]
                        const int* __restrict__ tok_id,
                        const int* __restrict__ counts,
                        const int* __restrict__ offsets,
                        unsigned short* __restrict__ hbuf) {      // [NSLOT][H]
  const int e = blockIdx.z;
  const int cnt = counts[e];
  const int mtile = blockIdx.y;
  if (mtile * 128 >= cnt) return;
  const int ntile = blockIdx.x;
  const int off = offsets[e];

  __shared__ __align__(16) unsigned short As[128 * 64];
  __shared__ __align__(16) unsigned short Bs[128 * 64];

  const int t = threadIdx.x;
  const int lane = t & 63;
  const int wave = t >> 6;
  const int wm = (wave >> 1) * 64;
  const int wn = (wave & 1) * 64;
  const int srow = t >> 3;                  // LDS row within 32-row plane
  const int seg = (t & 7) ^ (srow & 7);     // XOR-swizzled source chunk

  const unsigned short* aptr[4];
  const unsigned short* bptr[4];
#pragma unroll
  for (int p = 0; p < 4; ++p) {
    int r = mtile * 128 + p * 32 + srow;
    r = (r < cnt) ? r : (cnt - 1);  // clamp: masked at store
    int tok = tok_id[off + r];
    aptr[p] = xb + (size_t)tok * D_DIM + seg * 8;
    int br = ntile * 128 + p * 32 + srow;
    bptr[p] = wfc + ((size_t)e * H_DIM + br) * D_DIM + seg * 8;
  }

  f32x4 acc[4][4];
#pragma unroll
  for (int i = 0; i < 4; ++i)
#pragma unroll
    for (int j = 0; j < 4; ++j) acc[i][j] = (f32x4){0.f, 0.f, 0.f, 0.f};

  const int frow_a = wm + (lane & 15);
  const int frow_b = wn + (lane & 15);
  const int q = lane >> 4;
  const int csw = lane & 7;  // == frow&7 for both A and B (wm,wn mult of 64)

  for (int k0 = 0; k0 < D_DIM; k0 += 64) {
#pragma unroll
    for (int p = 0; p < 4; ++p) {
      gld_lds16(aptr[p] + k0, &As[p * 2048 + t * 8]);
      gld_lds16(bptr[p] + k0, &Bs[p * 2048 + t * 8]);
    }
    __syncthreads();
#pragma unroll
    for (int kk = 0; kk < 64; kk += 32) {
      const int ca = ((((kk >> 3) + q) ^ csw) << 3);
      bf16x8 af[4], bfr[4];
#pragma unroll
      for (int i = 0; i < 4; ++i)
        af[i] = *(const bf16x8*)&As[(frow_a + i * 16) * 64 + ca];
#pragma unroll
      for (int j = 0; j < 4; ++j)
        bfr[j] = *(const bf16x8*)&Bs[(frow_b + j * 16) * 64 + ca];
#pragma unroll
      for (int i = 0; i < 4; ++i)
#pragma unroll
        for (int j = 0; j < 4; ++j)
          acc[i][j] = __builtin_amdgcn_mfma_f32_16x16x32_bf16(af[i], bfr[j], acc[i][j], 0, 0, 0);
    }
    __syncthreads();
  }

  // epilogue: h = relu(t)^2, cast bf16, store
  const int lm = (lane >> 4) * 4;
  const int ln = lane & 15;
#pragma unroll
  for (int i = 0; i < 4; ++i) {
#pragma unroll
    for (int r = 0; r < 4; ++r) {
      int m = mtile * 128 + wm + i * 16 + lm + r;
      if (m < cnt) {
        size_t rowbase = (size_t)(off + m) * H_DIM + ntile * 128 + wn;
#pragma unroll
        for (int j = 0; j < 4; ++j) {
          float v = acc[i][j][r];
          v = v > 0.f ? v * v : 0.f;
          hbuf[rowbase + j * 16 + ln] = f2bf(v);
        }
      }
    }
  }
}

// split-K=2: z = e*2 + khalf. R2 showed only ~512 active blocks (2/CU,
// Occupancy 18%); split-K doubles co-resident blocks to 4/CU (LDS cap 5).
// Both halves atomicAdd into zero-initialized out.
__launch_bounds__(256, 2)
__global__ void gemm_proj(const unsigned short* __restrict__ hbuf,   // [NSLOT][H]
                          const unsigned short* __restrict__ wproj,  // [E][D][H]
                          const int* __restrict__ tok_id,
                          const float* __restrict__ tok_w,
                          const int* __restrict__ counts,
                          const int* __restrict__ offsets,
                          float* __restrict__ out) {                 // [N_TOK][D]
  const int e = blockIdx.z >> 1;
  const int kbase = (blockIdx.z & 1) * (H_DIM / 2);
  const int cnt = counts[e];
  const int mtile = blockIdx.y;
  if (mtile * 128 >= cnt) return;
  const int ntile = blockIdx.x;  // 0..7 (D=1024)
  const int off = offsets[e];

  __shared__ __align__(16) unsigned short As[128 * 64];
  __shared__ __align__(16) unsigned short Bs[128 * 64];

  const int t = threadIdx.x;
  const int lane = t & 63;
  const int wave = t >> 6;
  const int wm = (wave >> 1) * 64;
  const int wn = (wave & 1) * 64;
  const int srow = t >> 3;
  const int seg = (t & 7) ^ (srow & 7);  // XOR-swizzled source chunk

  const unsigned short* aptr[4];
  const unsigned short* bptr[4];
#pragma unroll
  for (int p = 0; p < 4; ++p) {
    int r = mtile * 128 + p * 32 + srow;
    r = (r < cnt) ? r : (cnt - 1);
    aptr[p] = hbuf + (size_t)(off + r) * H_DIM + seg * 8;
    int br = ntile * 128 + p * 32 + srow;
    bptr[p] = wproj + ((size_t)e * D_DIM + br) * H_DIM + seg * 8;
  }

  f32x4 acc[4][4];
#pragma unroll
  for (int i = 0; i < 4; ++i)
#pragma unroll
    for (int j = 0; j < 4; ++j) acc[i][j] = (f32x4){0.f, 0.f, 0.f, 0.f};

  const int frow_a = wm + (lane & 15);
  const int frow_b = wn + (lane & 15);
  const int q = lane >> 4;
  const int csw = lane & 7;

  for (int k0 = kbase; k0 < kbase + H_DIM / 2; k0 += 64) {
#pragma unroll
    for (int p = 0; p < 4; ++p) {
      gld_lds16(aptr[p] + k0, &As[p * 2048 + t * 8]);
      gld_lds16(bptr[p] + k0, &Bs[p * 2048 + t * 8]);
    }
    __syncthreads();
#pragma unroll
    for (int kk = 0; kk < 64; kk += 32) {
      const int ca = ((((kk >> 3) + q) ^ csw) << 3);
      bf16x8 af[4], bfr[4];
#pragma unroll
      for (int i = 0; i < 4; ++i)
        af[i] = *(const bf16x8*)&As[(frow_a + i * 16) * 64 + ca];
#pragma unroll
      for (int j = 0; j < 4; ++j)
        bfr[j] = *(const bf16x8*)&Bs[(frow_b + j * 16) * 64 + ca];
#pragma unroll
      for (int i = 0; i < 4; ++i)
#pragma unroll
        for (int j = 0; j < 4; ++j)
          acc[i][j] = __builtin_amdgcn_mfma_f32_16x16x32_bf16(af[i], bfr[j], acc[i][j], 0, 0, 0);
    }
    __syncthreads();
  }

  // epilogue: scale by routing weight, scatter-add into out
  const int lm = (lane >> 4) * 4;
  const int ln = lane & 15;
#pragma unroll
  for (int i = 0; i < 4; ++i) {
#pragma unroll
    for (int r = 0; r < 4; ++r) {
      int m = mtile * 128 + wm + i * 16 + lm + r;
      if (m < cnt) {
        int slot = off + m;
        float w = tok_w[slot];
        float* orow = out + (size_t)tok_id[slot] * D_DIM + ntile * 128 + wn;
#pragma unroll
        for (int j = 0; j < 4; ++j)
          atomicAdd(&orow[j * 16 + ln], acc[i][j][r] * w);
      }
    }
  }
}

// ---------------- launch ----------------
// ws layout (bytes):
//   0        counts[8] | 64 cursor[8] | 128 offsets[8]
//   256      eidx[4096] | 16640 rw[8192] | 49408 tok_id[8192] | 82176 tok_w[8192]
//   114944   probs[4096*8]         (131072)
//   246016   x_bf16                (8388608)
//   8634624  wfc_bf16              (67108864)
//   75743488 wproj_bf16            (67108864)
//   142852352 hbuf                 (67108864)

extern "C" void kernel_launch(void* const* d_in, const int* in_sizes, int n_in,
                              void* d_out, int out_size, void* d_ws, size_t ws_size,
                              hipStream_t stream) {
  (void)in_sizes; (void)n_in; (void)out_size; (void)ws_size;
  const float* x = (const float*)d_in[0];
  const float* wg = (const float*)d_in[1];
  const float* wfc = (const float*)d_in[2];
  const float* wproj = (const float*)d_in[3];
  float* out = (float*)d_out;
  char* ws = (char*)d_ws;

  int* counts = (int*)(ws + 0);
  int* cursor = (int*)(ws + 64);
  int* offsets = (int*)(ws + 128);
  int* eidx = (int*)(ws + 256);
  float* rw = (float*)(ws + 16640);
  int* tok_id = (int*)(ws + 49408);
  float* tok_w = (float*)(ws + 82176);
  float* probs = (float*)(ws + 114944);
  unsigned short* xb = (unsigned short*)(ws + 246016);
  unsigned short* wfcb = (unsigned short*)(ws + 8634624);
  unsigned short* wpjb = (unsigned short*)(ws + 75743488);
  unsigned short* hbuf = (unsigned short*)(ws + 142852352);

  hipLaunchKernelGGL(init_ctrl, dim3(1), dim3(64), 0, stream, (int*)ws);
  hipLaunchKernelGGL(cvt_f32_bf16, dim3(32768), dim3(256), 0, stream, wfc, wfcb, 8388608);
  hipLaunchKernelGGL(cvt_f32_bf16, dim3(32768), dim3(256), 0, stream, wproj, wpjb, 8388608);
  hipLaunchKernelGGL(cvt_f32_bf16, dim3(4096), dim3(256), 0, stream, x, xb, 1048576);
  hipLaunchKernelGGL(zero_f32, dim3(4096), dim3(256), 0, stream, out, 1048576);
  hipLaunchKernelGGL(gating_kernel, dim3(256), dim3(256), 0, stream, x, wg, probs, eidx, rw);
  hipLaunchKernelGGL(reduce_route, dim3(1), dim3(256), 0, stream, probs, eidx, counts, offsets, out + 4194304);
  hipLaunchKernelGGL(scatter_kernel, dim3(16), dim3(256), 0, stream, eidx, rw, offsets, cursor, tok_id, tok_w);
  hipLaunchKernelGGL(gemm_fc, dim3(32, 32, 8), dim3(256), 0, stream, xb, wfcb, tok_id, counts, offsets, hbuf);
  hipLaunchKernelGGL(gemm_proj, dim3(8, 32, 16), dim3(256), 0, stream, hbuf, wpjb, tok_id, tok_w, counts, offsets, out);
}